// Round 6
// baseline (215.864 us; speedup 1.0000x reference)
//
#include <hip/hip_runtime.h>

// ---------------- problem constants ----------------
#define LL 2048
#define BB 16
#define HH 512
#define PP 256
#define MM (LL*BB)   // 32768 rows
#define NN 512
#define KK 512
#define NC 64        // scan chunks
#define CLEN 32
#define BKF 32       // gemmF K-step
#define NKF 16       // 512/32

typedef __bf16 bf16x8 __attribute__((ext_vector_type(8)));
typedef float  f32x4  __attribute__((ext_vector_type(4)));

__device__ __forceinline__ unsigned short f2bf(float f) {
  unsigned u = __builtin_bit_cast(unsigned, f);
  u = (u + 0x7fffu + ((u >> 16) & 1u)) >> 16;   // RNE
  return (unsigned short)u;
}
__device__ __forceinline__ float bf2f(unsigned short s) {
  unsigned u = ((unsigned)s) << 16;
  return __builtin_bit_cast(float, u);
}

// ---------------- dtype detection for `d` ----------------
__global__ void detect_kernel(const unsigned int* __restrict__ dw, int* __restrict__ flag) {
  __shared__ int sInt, sFloat;
  if (threadIdx.x == 0) { sInt = 1; sFloat = 1; }
  __syncthreads();
  int allInt = 1, allFloat = 1;
  for (int i = threadIdx.x; i < 8192; i += 256) {
    unsigned v = dw[i];
    if (v > 1u) allInt = 0;
    if (v != 0u && v != 0x3f800000u) allFloat = 0;
  }
  if (!allInt) atomicAnd(&sInt, 0);
  if (!allFloat) atomicAnd(&sFloat, 0);
  __syncthreads();
  if (threadIdx.x == 0) *flag = sInt ? 0 : (sFloat ? 1 : 2);
}

__device__ __forceinline__ float keep_val(const void* d, int flag, int idx) {
  if (flag == 0) return 1.f - (float)((const int*)d)[idx];
  if (flag == 1) return 1.f - ((const float*)d)[idx];
  return 1.f - (float)((const unsigned char*)d)[idx];
}

// ---------------- weight precompute ----------------
__global__ void precompute_kernel(
    const float* __restrict__ Lre, const float* __restrict__ Lim,
    const float* __restrict__ Bre, const float* __restrict__ Bim,
    const float* __restrict__ Cre, const float* __restrict__ Cim,
    const float* __restrict__ lstep, const float* __restrict__ w2,
    unsigned short* __restrict__ W1t, unsigned short* __restrict__ W2t,
    unsigned short* __restrict__ W3t, float* __restrict__ lam_re,
    float* __restrict__ lam_im) {
  int t = blockIdx.x * 256 + threadIdx.x;   // 0..262143
  int k = t & (KK - 1);
  int n = t >> 9;
  {
    int p = n & (PP - 1);
    float lr = Lre[p], li = Lim[p];
    float st = expf(lstep[p]);
    float er = expf(lr * st);
    float ang = li * st;
    float lbr = er * cosf(ang), lbi = er * sinf(ang);
    float den = lr * lr + li * li;
    float wr = ((lbr - 1.f) * lr + lbi * li) / den;
    float wi = (lbi * lr - (lbr - 1.f) * li) / den;
    float br = Bre[p * HH + k], bi = Bim[p * HH + k];
    float v = (n < PP) ? (wr * br - wi * bi) : (wr * bi + wi * br);
    W1t[(size_t)n * KK + k] = f2bf(v);
  }
  {
    float v = (k < PP) ? (2.f * Cre[n * PP + k]) : (-2.f * Cim[n * PP + (k - PP)]);
    W2t[(size_t)n * KK + k] = f2bf(v);
  }
  W3t[(size_t)n * KK + k] = f2bf(w2[(size_t)k * HH + n]);
  if (t < PP) {
    float lr = Lre[t], li = Lim[t];
    float st = expf(lstep[t]);
    float er = expf(lr * st);
    float ang = li * st;
    lam_re[t] = er * cosf(ang);
    lam_im[t] = er * sinf(ang);
  }
}

// ---------------- LayerNorm (1 wave per 512-wide row, 4 rows/block) -------------
__global__ void ln1_kernel(const float* __restrict__ x, const float* __restrict__ sc,
                           const float* __restrict__ bs, unsigned short* __restrict__ xn) {
  int row = blockIdx.x * 4 + (threadIdx.x >> 6);
  int lane = threadIdx.x & 63;
  const float4* xr = (const float4*)(x + (size_t)row * HH) + lane * 2;
  float4 a = xr[0], b = xr[1];
  float s = (a.x + a.y) + (a.z + a.w) + (b.x + b.y) + (b.z + b.w);
  float q = a.x * a.x + a.y * a.y + a.z * a.z + a.w * a.w +
            b.x * b.x + b.y * b.y + b.z * b.z + b.w * b.w;
#pragma unroll
  for (int off = 32; off; off >>= 1) { s += __shfl_xor(s, off); q += __shfl_xor(q, off); }
  float mean = s * (1.f / HH);
  float var = fmaxf(q * (1.f / HH) - mean * mean, 0.f);
  float rstd = rsqrtf(var + 1e-6f);
  const float4* scp = (const float4*)sc + lane * 2;
  const float4* bsp = (const float4*)bs + lane * 2;
  float4 s0 = scp[0], s1 = scp[1], b0 = bsp[0], b1 = bsp[1];
  unsigned short o[8];
  o[0] = f2bf((a.x - mean) * rstd * s0.x + b0.x);
  o[1] = f2bf((a.y - mean) * rstd * s0.y + b0.y);
  o[2] = f2bf((a.z - mean) * rstd * s0.z + b0.z);
  o[3] = f2bf((a.w - mean) * rstd * s0.w + b0.w);
  o[4] = f2bf((b.x - mean) * rstd * s1.x + b1.x);
  o[5] = f2bf((b.y - mean) * rstd * s1.y + b1.y);
  o[6] = f2bf((b.z - mean) * rstd * s1.z + b1.z);
  o[7] = f2bf((b.w - mean) * rstd * s1.w + b1.w);
  uint4 pk;
  pk.x = o[0] | ((unsigned)o[1] << 16);
  pk.y = o[2] | ((unsigned)o[3] << 16);
  pk.z = o[4] | ((unsigned)o[5] << 16);
  pk.w = o[6] | ((unsigned)o[7] << 16);
  *((uint4*)(xn + (size_t)row * HH) + lane) = pk;
}

// ================= unified full-N GEMM: C[m,:] = A[m,:] @ Wt^T, BM=128, BN=512 ======
// 256 blocks, 1024 thr = 16 waves (2 wr x 8 wc), wave tile 64x64, BK=32, 16 K-iters.
// LDS: A 4 bufs x 8KB = 32KB, B 3 bufs x 32KB = 96KB @offset 32KB. 128KB total.
// Counted vmcnt schedule (FIFO-derived): iter k issues B(k+2), A(k+3); steady drain
// vmcnt(4) [A-staging waves w<8] / vmcnt(2) [w>=8]; tail k==13: (3,2); k>=14: 0.
// Epilogue: f32 LDS bounce in 4 chunks of 32 rows -> coalesced row pass per EPI:
//  EPI0: C=bf16(acc)                                    (GEMM1 -> Bu)
//  EPI1: val=acc+D*xn; LN(val); write y=bf16, x1=gelu(y) (GEMM2+ln2 fused)
//  EPI2: out=skip + y*sigmoid(acc+b2)  (f32)             (GEMM3)
template <int EPI>
__global__ __launch_bounds__(1024, 4) void gemmF_kernel(
    const unsigned short* __restrict__ A, const unsigned short* __restrict__ Wt,
    void* __restrict__ out0, unsigned short* __restrict__ out1,
    const unsigned short* __restrict__ aux16, const float* __restrict__ skip,
    const float* __restrict__ f1, const float* __restrict__ f2,
    const float* __restrict__ f3) {
  extern __shared__ unsigned short smem[];
  const int tid = threadIdx.x;
  const int w = tid >> 6, lane = tid & 63;
  const int wr = w >> 3, wc = w & 7;
  const int l15 = lane & 15, g16 = lane >> 4;
  const int m0 = blockIdx.x * 128;

  // staging geometry (16B slots, chunk-XOR both-sides swizzle: slot c holds src c^(row&3))
  const int aRow = (tid & 511) >> 2, aC = ((tid & 3) ^ (aRow & 3));
  const int bRow = tid >> 2,        bC = ((tid & 3) ^ (bRow & 3));

  auto sA = [&](int buf, int kt) {
    if (w < 8) {
      const unsigned short* g = A + (size_t)(m0 + aRow) * KK + kt * BKF + aC * 8;
      unsigned short* dp = smem + buf * 4096 + (w * 64) * 8;
      __builtin_amdgcn_global_load_lds((const __attribute__((address_space(1))) void*)g,
                                       (__attribute__((address_space(3))) void*)dp, 16, 0, 0);
    }
  };
  auto sB = [&](int buf, int kt) {
    const unsigned short* g = Wt + (size_t)bRow * KK + kt * BKF + bC * 8;
    unsigned short* dp = smem + 16384 + buf * 16384 + (w * 64) * 8;
    __builtin_amdgcn_global_load_lds((const __attribute__((address_space(1))) void*)g,
                                     (__attribute__((address_space(3))) void*)dp, 16, 0, 0);
    __builtin_amdgcn_global_load_lds(
        (const __attribute__((address_space(1))) void*)(g + (size_t)256 * KK),
        (__attribute__((address_space(3))) void*)(dp + 8192), 16, 0, 0);
  };
  auto rdA = [&](int buf, int fm) -> bf16x8 {
    int row = wr * 64 + fm * 16 + l15;
    return *(const bf16x8*)(smem + buf * 4096 + row * 32 + ((g16 ^ (row & 3)) * 8));
  };
  auto rdB = [&](int buf, int fn) -> bf16x8 {
    int row = wc * 64 + fn * 16 + l15;
    return *(const bf16x8*)(smem + 16384 + buf * 16384 + row * 32 + ((g16 ^ (row & 3)) * 8));
  };

  f32x4 acc[4][4];
#pragma unroll
  for (int i = 0; i < 4; i++)
#pragma unroll
    for (int j = 0; j < 4; j++) acc[i][j] = (f32x4){0.f, 0.f, 0.f, 0.f};

  // prologue: B0 A0 B1 A1 A2  (w<8 queue: B0,B0,A0,B1,B1,A1,A2 -> drain oldest 3)
  sB(0, 0); sA(0, 0); sB(1, 1); sA(1, 1); sA(2, 2);
  if (w < 8) asm volatile("s_waitcnt vmcnt(4)" ::: "memory");
  else       asm volatile("s_waitcnt vmcnt(2)" ::: "memory");
  __builtin_amdgcn_s_barrier();

#pragma unroll
  for (int k = 0; k < NKF; ++k) {
    if (k + 2 < NKF) sB((k + 2) % 3, k + 2);
    if (k + 3 < NKF) sA((k + 3) & 3, k + 3);
    bf16x8 aF[4];
#pragma unroll
    for (int fm = 0; fm < 4; fm++) aF[fm] = rdA(k & 3, fm);
    __builtin_amdgcn_s_setprio(1);
#pragma unroll
    for (int fn = 0; fn < 4; fn++) {
      bf16x8 bf = rdB(k % 3, fn);
#pragma unroll
      for (int fm = 0; fm < 4; fm++)
        acc[fm][fn] = __builtin_amdgcn_mfma_f32_16x16x32_bf16(aF[fm], bf, acc[fm][fn], 0, 0, 0);
    }
    __builtin_amdgcn_s_setprio(0);
    // pin ds_read completion before the barrier (rule #18)
    asm volatile("s_waitcnt lgkmcnt(0)" ::: "memory");
    __builtin_amdgcn_sched_barrier(0);
    if (k <= 12) {
      if (w < 8) asm volatile("s_waitcnt vmcnt(4)" ::: "memory");
      else       asm volatile("s_waitcnt vmcnt(2)" ::: "memory");
    } else if (k == 13) {
      if (w < 8) asm volatile("s_waitcnt vmcnt(3)" ::: "memory");
      else       asm volatile("s_waitcnt vmcnt(2)" ::: "memory");
    } else {
      asm volatile("s_waitcnt vmcnt(0)" ::: "memory");
    }
    __builtin_amdgcn_s_barrier();
  }

  // ---- epilogue: f32 bounce [32][512] in B region; 4 chunks of 32 rows ----
  float* lf = (float*)(smem + 16384);
  const int colb = lane * 8;
  float cD[8], cS[8], cB[8];
  if (EPI == 1) {
    *(float4*)&cD[0] = *(const float4*)&f1[colb]; *(float4*)&cD[4] = *(const float4*)&f1[colb + 4];
    *(float4*)&cS[0] = *(const float4*)&f2[colb]; *(float4*)&cS[4] = *(const float4*)&f2[colb + 4];
    *(float4*)&cB[0] = *(const float4*)&f3[colb]; *(float4*)&cB[4] = *(const float4*)&f3[colb + 4];
  } else if (EPI == 2) {
    *(float4*)&cD[0] = *(const float4*)&f1[colb]; *(float4*)&cD[4] = *(const float4*)&f1[colb + 4];
  }
  __syncthreads();
#pragma unroll
  for (int ch = 0; ch < 4; ++ch) {
    if (wr == (ch >> 1)) {
      int fmb = (ch & 1) * 2;
#pragma unroll
      for (int fmo = 0; fmo < 2; fmo++)
#pragma unroll
        for (int fn = 0; fn < 4; fn++) {
          int col = wc * 64 + fn * 16 + l15;
#pragma unroll
          for (int jj = 0; jj < 4; jj++)
            lf[(fmo * 16 + g16 * 4 + jj) * 512 + col] = acc[fmb + fmo][fn][jj];
        }
    }
    __syncthreads();
#pragma unroll
    for (int rr = 0; rr < 2; rr++) {
      int r = w * 2 + rr;
      int grow = m0 + ch * 32 + r;
      float4 v0 = *(const float4*)&lf[r * 512 + colb];
      float4 v1 = *(const float4*)&lf[r * 512 + colb + 4];
      float v[8] = { v0.x, v0.y, v0.z, v0.w, v1.x, v1.y, v1.z, v1.w };
      if (EPI == 0) {
        unsigned short o[8];
#pragma unroll
        for (int e = 0; e < 8; e++) o[e] = f2bf(v[e]);
        uint4 pk;
        pk.x = o[0] | ((unsigned)o[1] << 16); pk.y = o[2] | ((unsigned)o[3] << 16);
        pk.z = o[4] | ((unsigned)o[5] << 16); pk.w = o[6] | ((unsigned)o[7] << 16);
        *(uint4*)(((unsigned short*)out0) + (size_t)grow * NN + colb) = pk;
      } else if (EPI == 1) {
        uint4 xnv = *(const uint4*)(aux16 + (size_t)grow * NN + colb);
        unsigned xa[4] = { xnv.x, xnv.y, xnv.z, xnv.w };
        float val[8], s = 0.f, q = 0.f;
#pragma unroll
        for (int e = 0; e < 8; e++) {
          float xe = bf2f((unsigned short)((e & 1) ? (xa[e >> 1] >> 16) : (xa[e >> 1] & 0xffff)));
          val[e] = v[e] + cD[e] * xe;
          s += val[e]; q += val[e] * val[e];
        }
#pragma unroll
        for (int off = 32; off; off >>= 1) { s += __shfl_xor(s, off); q += __shfl_xor(q, off); }
        float mean = s * (1.f / HH);
        float var = fmaxf(q * (1.f / HH) - mean * mean, 0.f);
        float rstd = rsqrtf(var + 1e-6f);
        unsigned short oy[8], og[8];
#pragma unroll
        for (int e = 0; e < 8; e++) {
          float yv = (val[e] - mean) * rstd * cS[e] + cB[e];
          oy[e] = f2bf(yv);
          float g = 0.5f * yv * (1.f + tanhf(0.7978845608f * (yv + 0.044715f * yv * yv * yv)));
          og[e] = f2bf(g);
        }
        uint4 py, pg;
        py.x = oy[0] | ((unsigned)oy[1] << 16); py.y = oy[2] | ((unsigned)oy[3] << 16);
        py.z = oy[4] | ((unsigned)oy[5] << 16); py.w = oy[6] | ((unsigned)oy[7] << 16);
        pg.x = og[0] | ((unsigned)og[1] << 16); pg.y = og[2] | ((unsigned)og[3] << 16);
        pg.z = og[4] | ((unsigned)og[5] << 16); pg.w = og[6] | ((unsigned)og[7] << 16);
        *(uint4*)(((unsigned short*)out0) + (size_t)grow * NN + colb) = py;
        *(uint4*)(out1 + (size_t)grow * NN + colb) = pg;
      } else {
        uint4 yv4 = *(const uint4*)(aux16 + (size_t)grow * NN + colb);
        unsigned ya[4] = { yv4.x, yv4.y, yv4.z, yv4.w };
        float4 sk0 = *(const float4*)(skip + (size_t)grow * NN + colb);
        float4 sk1 = *(const float4*)(skip + (size_t)grow * NN + colb + 4);
        float sk[8] = { sk0.x, sk0.y, sk0.z, sk0.w, sk1.x, sk1.y, sk1.z, sk1.w };
        float o[8];
#pragma unroll
        for (int e = 0; e < 8; e++) {
          float ye = bf2f((unsigned short)((e & 1) ? (ya[e >> 1] >> 16) : (ya[e >> 1] & 0xffff)));
          float z = v[e] + cD[e];
          o[e] = sk[e] + ye / (1.f + expf(-z));
        }
        float* op = ((float*)out0) + (size_t)grow * NN + colb;
        *(float4*)op = (float4){ o[0], o[1], o[2], o[3] };
        *(float4*)(op + 4) = (float4){ o[4], o[5], o[6], o[7] };
      }
    }
    __syncthreads();
  }
}

// ---------------- chunked scan (Bu bf16) ----------------
__global__ void scanA_kernel(const unsigned short* __restrict__ Bu, const void* __restrict__ d,
                             const int* __restrict__ dflag, const float* __restrict__ lam_re,
                             const float* __restrict__ lam_im, float* __restrict__ Ar,
                             float* __restrict__ Ai, float* __restrict__ Sr,
                             float* __restrict__ Si) {
  int bx = blockIdx.x;  // c*16 + b
  int c = bx >> 4, b = bx & 15;
  int p = threadIdx.x;
  int fl = *dflag;
  float lr = lam_re[p], li = lam_im[p];
  float Apr = 1.f, Api = 0.f, sr = 0.f, si = 0.f;
  int l0 = c * CLEN;
  for (int j = 0; j < CLEN; j++) {
    int l = l0 + j;
    float kp = keep_val(d, fl, l * BB + b);
    float ar = lr * kp, ai = li * kp;
    size_t ro = (size_t)(l * BB + b) * NN;
    float bur = bf2f(Bu[ro + p]), bui = bf2f(Bu[ro + PP + p]);
    float nsr = ar * sr - ai * si + bur;
    float nsi = ar * si + ai * sr + bui;
    sr = nsr; si = nsi;
    float nar = ar * Apr - ai * Api;
    float nai = ar * Api + ai * Apr;
    Apr = nar; Api = nai;
  }
  int o = bx * PP + p;
  Ar[o] = Apr; Ai[o] = Api; Sr[o] = sr; Si[o] = si;
}

__global__ void scanB_kernel(const float* __restrict__ hr0, const float* __restrict__ hi0,
                             const float* __restrict__ Ar, const float* __restrict__ Ai,
                             const float* __restrict__ Sr, const float* __restrict__ Si,
                             float* __restrict__ Cr, float* __restrict__ Ci,
                             float* __restrict__ outHid) {
  int b = blockIdx.x;
  int p = threadIdx.x;
  float cr = hr0[b * PP + p], ci = hi0[b * PP + p];
  for (int c = 0; c < NC; c++) {
    int o = (c * BB + b) * PP + p;
    Cr[o] = cr; Ci[o] = ci;
    float ar = Ar[o], ai = Ai[o];
    float nr = ar * cr - ai * ci + Sr[o];
    float ni = ar * ci + ai * cr + Si[o];
    cr = nr; ci = ni;
  }
  outHid[b * PP + p] = cr;                 // new_hidden.real
  outHid[BB * PP + b * PP + p] = ci;       // new_hidden.imag
}

__global__ void scanC_kernel(const unsigned short* __restrict__ Bu, const void* __restrict__ d,
                             const int* __restrict__ dflag, const float* __restrict__ lam_re,
                             const float* __restrict__ lam_im, const float* __restrict__ Cr,
                             const float* __restrict__ Ci, unsigned short* __restrict__ xs) {
  int bx = blockIdx.x;
  int c = bx >> 4, b = bx & 15;
  int p = threadIdx.x;
  int fl = *dflag;
  float lr = lam_re[p], li = lam_im[p];
  float hr = Cr[bx * PP + p], hi = Ci[bx * PP + p];
  int l0 = c * CLEN;
  for (int j = 0; j < CLEN; j++) {
    int l = l0 + j;
    float kp = keep_val(d, fl, l * BB + b);
    float ar = lr * kp, ai = li * kp;
    size_t ro = (size_t)(l * BB + b) * NN;
    float bur = bf2f(Bu[ro + p]), bui = bf2f(Bu[ro + PP + p]);
    float nhr = ar * hr - ai * hi + bur;
    float nhi = ar * hi + ai * hr + bui;
    hr = nhr; hi = nhi;
    xs[ro + p] = f2bf(hr);
    xs[ro + PP + p] = f2bf(hi);
  }
}

// ---------------- launcher ----------------
extern "C" void kernel_launch(void* const* d_in, const int* in_sizes, int n_in,
                              void* d_out, int out_size, void* d_ws, size_t ws_size,
                              hipStream_t stream) {
  const float* x    = (const float*)d_in[0];
  const void*  dmask= d_in[1];
  const float* hidr = (const float*)d_in[2];
  const float* hidi = (const float*)d_in[3];
  const float* Lre  = (const float*)d_in[4];
  const float* Lim  = (const float*)d_in[5];
  const float* Bre  = (const float*)d_in[6];
  const float* Bim  = (const float*)d_in[7];
  const float* Cre  = (const float*)d_in[8];
  const float* Cim  = (const float*)d_in[9];
  const float* Dv   = (const float*)d_in[10];
  const float* lst  = (const float*)d_in[11];
  const float* lsc  = (const float*)d_in[12];
  const float* lbs  = (const float*)d_in[13];
  const float* w2   = (const float*)d_in[14];
  const float* b2   = (const float*)d_in[15];
  float* out = (float*)d_out;

  char* ws = (char*)d_ws;
  size_t off = 0;
  auto alloc = [&](size_t bytes) -> void* {
    void* p = ws + off;
    off += (bytes + 255) & ~(size_t)255;
    return p;
  };
  unsigned short* xn  = (unsigned short*)alloc((size_t)MM * KK * 2);  // 32MB
  unsigned short* xs  = (unsigned short*)alloc((size_t)MM * KK * 2);  // 32MB
  unsigned short* Bu  = (unsigned short*)alloc((size_t)MM * NN * 2);  // 32MB; reused as y
  unsigned short* x1  = (unsigned short*)alloc((size_t)MM * NN * 2);  // 32MB
  unsigned short* W1t = (unsigned short*)alloc((size_t)NN * KK * 2);
  unsigned short* W2t = (unsigned short*)alloc((size_t)NN * KK * 2);
  unsigned short* W3t = (unsigned short*)alloc((size_t)NN * KK * 2);
  float* lam_re = (float*)alloc(PP * 4);
  float* lam_im = (float*)alloc(PP * 4);
  float* Ar = (float*)alloc((size_t)NC * BB * PP * 4);
  float* Ai = (float*)alloc((size_t)NC * BB * PP * 4);
  float* Sr = (float*)alloc((size_t)NC * BB * PP * 4);
  float* Si = (float*)alloc((size_t)NC * BB * PP * 4);
  float* Cr = (float*)alloc((size_t)NC * BB * PP * 4);
  float* Ci = (float*)alloc((size_t)NC * BB * PP * 4);
  int* dflag = (int*)alloc(256);
  unsigned short* y = Bu;   // reuse Bu after scan consumed it

  hipFuncSetAttribute((const void*)gemmF_kernel<0>,
                      hipFuncAttributeMaxDynamicSharedMemorySize, 131072);
  hipFuncSetAttribute((const void*)gemmF_kernel<1>,
                      hipFuncAttributeMaxDynamicSharedMemorySize, 131072);
  hipFuncSetAttribute((const void*)gemmF_kernel<2>,
                      hipFuncAttributeMaxDynamicSharedMemorySize, 131072);

  detect_kernel<<<1, 256, 0, stream>>>((const unsigned int*)dmask, dflag);
  precompute_kernel<<<1024, 256, 0, stream>>>(Lre, Lim, Bre, Bim, Cre, Cim, lst, w2,
                                              W1t, W2t, W3t, lam_re, lam_im);
  ln1_kernel<<<MM / 4, 256, 0, stream>>>(x, lsc, lbs, xn);
  gemmF_kernel<0><<<256, 1024, 131072, stream>>>(xn, W1t, Bu, nullptr, nullptr, nullptr,
                                                 nullptr, nullptr, nullptr);
  scanA_kernel<<<NC * BB, 256, 0, stream>>>(Bu, dmask, dflag, lam_re, lam_im, Ar, Ai, Sr, Si);
  scanB_kernel<<<BB, 256, 0, stream>>>(hidr, hidi, Ar, Ai, Sr, Si, Cr, Ci, out);
  scanC_kernel<<<NC * BB, 256, 0, stream>>>(Bu, dmask, dflag, lam_re, lam_im, Cr, Ci, xs);
  gemmF_kernel<1><<<256, 1024, 131072, stream>>>(xs, W2t, y, x1, xn, nullptr, Dv, lsc, lbs);
  gemmF_kernel<2><<<256, 1024, 131072, stream>>>(x1, W3t, out + 2 * BB * PP, nullptr, y, x,
                                                 b2, nullptr, nullptr);
}